// Round 2
// baseline (100.465 us; speedup 1.0000x reference)
//
#include <hip/hip_runtime.h>

static constexpr int BATCH = 8;
static constexpr int NODES = 20000;
static constexpr int DEG   = 32;
static constexpr int NB    = 8;

#if defined(__has_builtin) && __has_builtin(__builtin_amdgcn_exp2f)
#define EXP2F(x) __builtin_amdgcn_exp2f(x)
#else
#define EXP2F(x) exp2f(x)
#endif

// RBF algebra: sigma = 2.5/8 = 0.3125, mu_k = k*2.5/7.
//   x_k = exp(-0.5((r-mu_k)/sigma)^2) = x_0 * g^k * prod_{j<k} h_j
//   x_0 = exp2(r^2 * C1),  C1 = -(0.5/sigma^2)*log2e = -5.12*1.44269504 = -7.3865986
//   g   = exp2(r * C2),    C2 = (mu_1/sigma^2)*log2e = 3.65714286*1.44269504 = 5.2761417
//   h_k = exp(-0.5*m^2*(2k+1)), m = mu_1/sigma = 1.14285714, 0.5*m^2 = 0.65306122
static constexpr float C1 = -7.3865986f;
static constexpr float C2 = 5.2761417f;

// Pack (B,N,3) fp32 positions into (B,N) float4 so each neighbor gather is a
// single global_load_dwordx4 on a single cache line (3x fewer scattered loads).
__global__ __launch_bounds__(256)
void pack_pos_kernel(const float* __restrict__ pos, float4* __restrict__ pos4) {
    const int t = blockIdx.x * blockDim.x + threadIdx.x;
    if (t >= BATCH * NODES) return;
    pos4[t] = make_float4(pos[3 * t + 0], pos[3 * t + 1], pos[3 * t + 2], 0.0f);
}

__global__ __launch_bounds__(256)
void graph_embed_kernel(const float4* __restrict__ pos4,  // (B,N) packed
                        const float* __restrict__ box,    // (3,)
                        const int*   __restrict__ nbr,    // (N, DEG)
                        float* __restrict__ out)          // y (B,N,8) ++ yv (B,N,8,3)
{
    const int t = blockIdx.x * blockDim.x + threadIdx.x;
    if (t >= BATCH * NODES) return;
    const int b = t / NODES;
    const int i = t - b * NODES;

    const float inv2pi = 0.15915494309189535f;
    const float ab0 = box[0] * inv2pi;
    const float ab1 = box[1] * inv2pi;
    const float ab2 = box[2] * inv2pi;
    const float ia0 = 1.0f / ab0;
    const float ia1 = 1.0f / ab1;
    const float ia2 = 1.0f / ab2;

    // h_k ladder constants (7 cheap exps per thread, amortized over 32 edges)
    float h[NB - 1];
#pragma unroll
    for (int k = 0; k < NB - 1; ++k)
        h[k] = __expf(-0.6530612245f * (float)(2 * k + 1));

    const float4* __restrict__ pb = pos4 + (size_t)b * NODES;
    const float4 p = pb[i];

    float y0[NB], v0[NB], v1[NB], v2[NB];
#pragma unroll
    for (int k = 0; k < NB; ++k) { y0[k] = 0.f; v0[k] = 0.f; v1[k] = 0.f; v2[k] = 0.f; }

    const int4* __restrict__ row = (const int4*)(nbr + (size_t)i * DEG);  // 128B line

    // Software pipeline: prefetch next group's indices + 4 gathers during compute.
    int4 idx = row[0];
    float4 q0 = pb[idx.x], q1 = pb[idx.y], q2 = pb[idx.z], q3 = pb[idx.w];

#pragma unroll
    for (int grp = 0; grp < DEG / 4; ++grp) {
        float4 n0, n1, n2, n3;
        if (grp + 1 < DEG / 4) {
            const int4 nidx = row[grp + 1];
            n0 = pb[nidx.x]; n1 = pb[nidx.y]; n2 = pb[nidx.z]; n3 = pb[nidx.w];
        }
        const float4 qs[4] = { q0, q1, q2, q3 };
#pragma unroll
        for (int jj = 0; jj < 4; ++jj) {
            const float4 q = qs[jj];
            const float e0 = ab0 * __sinf((q.x - p.x) * ia0);
            const float e1 = ab1 * __sinf((q.y - p.y) * ia1);
            const float e2 = ab2 * __sinf((q.z - p.z) * ia2);
            const float r  = fmaf(e0, e0, fmaf(e1, e1, e2 * e2));

            const float g = EXP2F(r * C2);          // exp(m*u)
            float x = EXP2F(r * r * C1);            // x_0 = exp(-0.5*u^2)
#pragma unroll
            for (int k = 0; k < NB; ++k) {
                y0[k] += x;
                v0[k] = fmaf(x, e0, v0[k]);
                v1[k] = fmaf(x, e1, v1[k]);
                v2[k] = fmaf(x, e2, v2[k]);
                if (k < NB - 1) x = x * g * h[k];
            }
        }
        q0 = n0; q1 = n1; q2 = n2; q3 = n3;
    }

    // y section: 2x float4
    float* __restrict__ yptr = out + (size_t)t * NB;
    *(float4*)(yptr + 0) = make_float4(y0[0], y0[1], y0[2], y0[3]);
    *(float4*)(yptr + 4) = make_float4(y0[4], y0[5], y0[6], y0[7]);

    // yv section: 6x float4 (24 floats, 96B-aligned per thread)
    float* __restrict__ vptr = out + (size_t)BATCH * NODES * NB + (size_t)t * (NB * 3);
    *(float4*)(vptr +  0) = make_float4(v0[0], v1[0], v2[0], v0[1]);
    *(float4*)(vptr +  4) = make_float4(v1[1], v2[1], v0[2], v1[2]);
    *(float4*)(vptr +  8) = make_float4(v2[2], v0[3], v1[3], v2[3]);
    *(float4*)(vptr + 12) = make_float4(v0[4], v1[4], v2[4], v0[5]);
    *(float4*)(vptr + 16) = make_float4(v1[5], v2[5], v0[6], v1[6]);
    *(float4*)(vptr + 20) = make_float4(v2[6], v0[7], v1[7], v2[7]);
}

// Fallback (ws too small): proven R1 kernel, 3-dword gathers straight from pos.
__global__ __launch_bounds__(256)
void graph_embed_fallback_kernel(const float* __restrict__ pos,
                                 const float* __restrict__ box,
                                 const int*   __restrict__ nbr,
                                 float* __restrict__ out)
{
    const int t = blockIdx.x * blockDim.x + threadIdx.x;
    if (t >= BATCH * NODES) return;
    const int b = t / NODES;
    const int i = t - b * NODES;

    const float inv2pi = 0.15915494309189535f;
    const float ab0 = box[0] * inv2pi, ab1 = box[1] * inv2pi, ab2 = box[2] * inv2pi;
    const float ia0 = 1.0f / ab0, ia1 = 1.0f / ab1, ia2 = 1.0f / ab2;

    float h[NB - 1];
#pragma unroll
    for (int k = 0; k < NB - 1; ++k)
        h[k] = __expf(-0.6530612245f * (float)(2 * k + 1));

    const float* __restrict__ pb = pos + (size_t)b * NODES * 3;
    const float p0 = pb[3 * i + 0], p1 = pb[3 * i + 1], p2 = pb[3 * i + 2];

    float y0[NB], v0[NB], v1[NB], v2[NB];
#pragma unroll
    for (int k = 0; k < NB; ++k) { y0[k] = 0.f; v0[k] = 0.f; v1[k] = 0.f; v2[k] = 0.f; }

    const int* __restrict__ row = nbr + (size_t)i * DEG;
#pragma unroll 4
    for (int j = 0; j < DEG; ++j) {
        const int idx = row[j];
        const float* __restrict__ q = pb + (size_t)idx * 3;
        const float e0 = ab0 * __sinf((q[0] - p0) * ia0);
        const float e1 = ab1 * __sinf((q[1] - p1) * ia1);
        const float e2 = ab2 * __sinf((q[2] - p2) * ia2);
        const float r  = fmaf(e0, e0, fmaf(e1, e1, e2 * e2));
        const float g = EXP2F(r * C2);
        float x = EXP2F(r * r * C1);
#pragma unroll
        for (int k = 0; k < NB; ++k) {
            y0[k] += x;
            v0[k] = fmaf(x, e0, v0[k]);
            v1[k] = fmaf(x, e1, v1[k]);
            v2[k] = fmaf(x, e2, v2[k]);
            if (k < NB - 1) x = x * g * h[k];
        }
    }

    float* __restrict__ yptr = out + (size_t)t * NB;
    *(float4*)(yptr + 0) = make_float4(y0[0], y0[1], y0[2], y0[3]);
    *(float4*)(yptr + 4) = make_float4(y0[4], y0[5], y0[6], y0[7]);
    float* __restrict__ vptr = out + (size_t)BATCH * NODES * NB + (size_t)t * (NB * 3);
    *(float4*)(vptr +  0) = make_float4(v0[0], v1[0], v2[0], v0[1]);
    *(float4*)(vptr +  4) = make_float4(v1[1], v2[1], v0[2], v1[2]);
    *(float4*)(vptr +  8) = make_float4(v2[2], v0[3], v1[3], v2[3]);
    *(float4*)(vptr + 12) = make_float4(v0[4], v1[4], v2[4], v0[5]);
    *(float4*)(vptr + 16) = make_float4(v1[5], v2[5], v0[6], v1[6]);
    *(float4*)(vptr + 20) = make_float4(v2[6], v0[7], v1[7], v2[7]);
}

extern "C" void kernel_launch(void* const* d_in, const int* in_sizes, int n_in,
                              void* d_out, int out_size, void* d_ws, size_t ws_size,
                              hipStream_t stream) {
    const float* pos = (const float*)d_in[0];   // (8, 20000, 3) fp32
    const float* box = (const float*)d_in[1];   // (3,) fp32
    const int*   nbr = (const int*)d_in[2];     // (20000, 32) int32
    float* out = (float*)d_out;

    const int total = BATCH * NODES;
    const int block = 256;
    const int grid  = (total + block - 1) / block;

    const size_t packed_bytes = (size_t)total * sizeof(float4);  // 5.12 MB
    if (ws_size >= packed_bytes) {
        float4* pos4 = (float4*)d_ws;
        pack_pos_kernel<<<grid, block, 0, stream>>>(pos, pos4);
        graph_embed_kernel<<<grid, block, 0, stream>>>(pos4, box, nbr, out);
    } else {
        graph_embed_fallback_kernel<<<grid, block, 0, stream>>>(pos, box, nbr, out);
    }
}

// Round 3
// 87.961 us; speedup vs baseline: 1.1422x; 1.1422x over previous
//
#include <hip/hip_runtime.h>

static constexpr int BATCH = 8;
static constexpr int NODES = 20000;
static constexpr int DEG   = 32;
static constexpr int NB    = 8;

#if defined(__has_builtin) && __has_builtin(__builtin_amdgcn_exp2f)
#define EXP2F(x) __builtin_amdgcn_exp2f(x)
#else
#define EXP2F(x) exp2f(x)
#endif

// RBF algebra: sigma = 2.5/8, mu_k = k*2.5/7.
//   x_k = x_0 * g^k * prod_{j<k} h_j
//   x_0 = exp2(r^2 * C1), C1 = -(0.5/sigma^2)*log2e
//   g   = exp2(r * C2),   C2 = (mu_1/sigma^2)*log2e
//   h_k = exp(-0.65306122*(2k+1))
static constexpr float C1 = -7.3865986f;
static constexpr float C2 = 5.2761417f;

// Transpose pos (B,N,3) -> pos_t (N,B) float4, so the 8 batch copies of one
// node are one contiguous 128B-aligned segment (single cache line).
__global__ __launch_bounds__(256)
void transpose_pos_kernel(const float* __restrict__ pos, float4* __restrict__ pos_t) {
    const int t = blockIdx.x * blockDim.x + threadIdx.x;   // t = b*N + i (coalesced read)
    if (t >= BATCH * NODES) return;
    const int b = t / NODES;
    const int i = t - b * NODES;
    pos_t[(size_t)i * BATCH + b] =
        make_float4(pos[3 * t + 0], pos[3 * t + 1], pos[3 * t + 2], 0.0f);
}

__global__ __launch_bounds__(256)
void graph_embed_kernel(const float4* __restrict__ pos_t,  // (N, B) packed
                        const float* __restrict__ box,     // (3,)
                        const int*   __restrict__ nbr,     // (N, DEG)
                        float* __restrict__ out)           // y (B,N,8) ++ yv (B,N,8,3)
{
    const int t = blockIdx.x * blockDim.x + threadIdx.x;
    if (t >= BATCH * NODES) return;
    // batch-fastest lane mapping: 8 lanes of one node gather one 128B line
    const int i = t >> 3;       // node
    const int b = t & 7;        // batch

    const float inv2pi = 0.15915494309189535f;
    const float ab0 = box[0] * inv2pi;
    const float ab1 = box[1] * inv2pi;
    const float ab2 = box[2] * inv2pi;
    const float ia0 = 1.0f / ab0;
    const float ia1 = 1.0f / ab1;
    const float ia2 = 1.0f / ab2;

    float h[NB - 1];
#pragma unroll
    for (int k = 0; k < NB - 1; ++k)
        h[k] = __expf(-0.6530612245f * (float)(2 * k + 1));

    const float4 p = pos_t[(size_t)i * BATCH + b];

    float y0[NB], v0[NB], v1[NB], v2[NB];
#pragma unroll
    for (int k = 0; k < NB; ++k) { y0[k] = 0.f; v0[k] = 0.f; v1[k] = 0.f; v2[k] = 0.f; }

    // 8 lanes share the same row -> broadcast loads (8 lines/wave instead of 64)
    const int4* __restrict__ row = (const int4*)(nbr + (size_t)i * DEG);

    int4 idx = row[0];
    float4 q0 = pos_t[(size_t)idx.x * BATCH + b];
    float4 q1 = pos_t[(size_t)idx.y * BATCH + b];
    float4 q2 = pos_t[(size_t)idx.z * BATCH + b];
    float4 q3 = pos_t[(size_t)idx.w * BATCH + b];

#pragma unroll
    for (int grp = 0; grp < DEG / 4; ++grp) {
        float4 n0, n1, n2, n3;
        if (grp + 1 < DEG / 4) {
            const int4 nidx = row[grp + 1];
            n0 = pos_t[(size_t)nidx.x * BATCH + b];
            n1 = pos_t[(size_t)nidx.y * BATCH + b];
            n2 = pos_t[(size_t)nidx.z * BATCH + b];
            n3 = pos_t[(size_t)nidx.w * BATCH + b];
        }
        const float4 qs[4] = { q0, q1, q2, q3 };
#pragma unroll
        for (int jj = 0; jj < 4; ++jj) {
            const float4 q = qs[jj];
            const float e0 = ab0 * __sinf((q.x - p.x) * ia0);
            const float e1 = ab1 * __sinf((q.y - p.y) * ia1);
            const float e2 = ab2 * __sinf((q.z - p.z) * ia2);
            const float r  = fmaf(e0, e0, fmaf(e1, e1, e2 * e2));

            const float g = EXP2F(r * C2);
            float x = EXP2F(r * r * C1);
#pragma unroll
            for (int k = 0; k < NB; ++k) {
                y0[k] += x;
                v0[k] = fmaf(x, e0, v0[k]);
                v1[k] = fmaf(x, e1, v1[k]);
                v2[k] = fmaf(x, e2, v2[k]);
                if (k < NB - 1) x = x * g * h[k];
            }
        }
        q0 = n0; q1 = n1; q2 = n2; q3 = n3;
    }

    // Per-lane contiguous chunks; same-wave lanes tile full lines (HW-coalesced).
    const size_t ot = (size_t)b * NODES + i;
    float* __restrict__ yptr = out + ot * NB;
    *(float4*)(yptr + 0) = make_float4(y0[0], y0[1], y0[2], y0[3]);
    *(float4*)(yptr + 4) = make_float4(y0[4], y0[5], y0[6], y0[7]);

    float* __restrict__ vptr = out + (size_t)BATCH * NODES * NB + ot * (NB * 3);
    *(float4*)(vptr +  0) = make_float4(v0[0], v1[0], v2[0], v0[1]);
    *(float4*)(vptr +  4) = make_float4(v1[1], v2[1], v0[2], v1[2]);
    *(float4*)(vptr +  8) = make_float4(v2[2], v0[3], v1[3], v2[3]);
    *(float4*)(vptr + 12) = make_float4(v0[4], v1[4], v2[4], v0[5]);
    *(float4*)(vptr + 16) = make_float4(v1[5], v2[5], v0[6], v1[6]);
    *(float4*)(vptr + 20) = make_float4(v2[6], v0[7], v1[7], v2[7]);
}

// Fallback (ws too small): R2 kernel reading pos directly, i-fast mapping.
__global__ __launch_bounds__(256)
void graph_embed_fallback_kernel(const float* __restrict__ pos,
                                 const float* __restrict__ box,
                                 const int*   __restrict__ nbr,
                                 float* __restrict__ out)
{
    const int t = blockIdx.x * blockDim.x + threadIdx.x;
    if (t >= BATCH * NODES) return;
    const int b = t / NODES;
    const int i = t - b * NODES;

    const float inv2pi = 0.15915494309189535f;
    const float ab0 = box[0] * inv2pi, ab1 = box[1] * inv2pi, ab2 = box[2] * inv2pi;
    const float ia0 = 1.0f / ab0, ia1 = 1.0f / ab1, ia2 = 1.0f / ab2;

    float h[NB - 1];
#pragma unroll
    for (int k = 0; k < NB - 1; ++k)
        h[k] = __expf(-0.6530612245f * (float)(2 * k + 1));

    const float* __restrict__ pb = pos + (size_t)b * NODES * 3;
    const float p0 = pb[3 * i + 0], p1 = pb[3 * i + 1], p2 = pb[3 * i + 2];

    float y0[NB], v0[NB], v1[NB], v2[NB];
#pragma unroll
    for (int k = 0; k < NB; ++k) { y0[k] = 0.f; v0[k] = 0.f; v1[k] = 0.f; v2[k] = 0.f; }

    const int* __restrict__ row = nbr + (size_t)i * DEG;
#pragma unroll 4
    for (int j = 0; j < DEG; ++j) {
        const int idx = row[j];
        const float* __restrict__ q = pb + (size_t)idx * 3;
        const float e0 = ab0 * __sinf((q[0] - p0) * ia0);
        const float e1 = ab1 * __sinf((q[1] - p1) * ia1);
        const float e2 = ab2 * __sinf((q[2] - p2) * ia2);
        const float r  = fmaf(e0, e0, fmaf(e1, e1, e2 * e2));
        const float g = EXP2F(r * C2);
        float x = EXP2F(r * r * C1);
#pragma unroll
        for (int k = 0; k < NB; ++k) {
            y0[k] += x;
            v0[k] = fmaf(x, e0, v0[k]);
            v1[k] = fmaf(x, e1, v1[k]);
            v2[k] = fmaf(x, e2, v2[k]);
            if (k < NB - 1) x = x * g * h[k];
        }
    }

    float* __restrict__ yptr = out + (size_t)t * NB;
    *(float4*)(yptr + 0) = make_float4(y0[0], y0[1], y0[2], y0[3]);
    *(float4*)(yptr + 4) = make_float4(y0[4], y0[5], y0[6], y0[7]);
    float* __restrict__ vptr = out + (size_t)BATCH * NODES * NB + (size_t)t * (NB * 3);
    *(float4*)(vptr +  0) = make_float4(v0[0], v1[0], v2[0], v0[1]);
    *(float4*)(vptr +  4) = make_float4(v1[1], v2[1], v0[2], v1[2]);
    *(float4*)(vptr +  8) = make_float4(v2[2], v0[3], v1[3], v2[3]);
    *(float4*)(vptr + 12) = make_float4(v0[4], v1[4], v2[4], v0[5]);
    *(float4*)(vptr + 16) = make_float4(v1[5], v2[5], v0[6], v1[6]);
    *(float4*)(vptr + 20) = make_float4(v2[6], v0[7], v1[7], v2[7]);
}

extern "C" void kernel_launch(void* const* d_in, const int* in_sizes, int n_in,
                              void* d_out, int out_size, void* d_ws, size_t ws_size,
                              hipStream_t stream) {
    const float* pos = (const float*)d_in[0];   // (8, 20000, 3) fp32
    const float* box = (const float*)d_in[1];   // (3,) fp32
    const int*   nbr = (const int*)d_in[2];     // (20000, 32) int32
    float* out = (float*)d_out;

    const int total = BATCH * NODES;
    const int block = 256;
    const int grid  = (total + block - 1) / block;

    const size_t packed_bytes = (size_t)total * sizeof(float4);  // 5.12 MB
    if (ws_size >= packed_bytes) {
        float4* pos_t = (float4*)d_ws;
        transpose_pos_kernel<<<grid, block, 0, stream>>>(pos, pos_t);
        graph_embed_kernel<<<grid, block, 0, stream>>>(pos_t, box, nbr, out);
    } else {
        graph_embed_fallback_kernel<<<grid, block, 0, stream>>>(pos, box, nbr, out);
    }
}

// Round 4
// 83.939 us; speedup vs baseline: 1.1969x; 1.0479x over previous
//
#include <hip/hip_runtime.h>

static constexpr int BATCH = 8;
static constexpr int NODES = 20000;
static constexpr int DEG   = 32;
static constexpr int NB    = 8;

#if defined(__has_builtin) && __has_builtin(__builtin_amdgcn_exp2f)
#define EXP2F(x) __builtin_amdgcn_exp2f(x)
#else
#define EXP2F(x) exp2f(x)
#endif

// RBF algebra: sigma = 2.5/8, mu_k = k*2.5/7.
//   x_k = x_0 * g^k * prod_{j<k} h_j
//   x_0 = exp2(r^2 * C1), C1 = -(0.5/sigma^2)*log2e
//   g   = exp2(r * C2),   C2 = (mu_1/sigma^2)*log2e
//   h_k = exp(-0.65306122*(2k+1))
static constexpr float C1 = -7.3865986f;
static constexpr float C2 = 5.2761417f;

// pos (B,N,3) -> pos_t (N,B) float4: the 8 batch copies of a node are one
// 128B-aligned cache line, so an 8-lane b-group gathers exactly one line.
__global__ __launch_bounds__(256)
void transpose_pos_kernel(const float* __restrict__ pos, float4* __restrict__ pos_t) {
    const int t = blockIdx.x * blockDim.x + threadIdx.x;
    if (t >= BATCH * NODES) return;
    const int b = t / NODES;
    const int i = t - b * NODES;
    pos_t[(size_t)i * BATCH + b] =
        make_float4(pos[3 * t + 0], pos[3 * t + 1], pos[3 * t + 2], 0.0f);
}

// Thread per (node i, batch b, deg-half jh). 320k threads -> 5000 waves
// (~4.9/SIMD residency) for latency hiding; halves combined by shfl_xor(8).
// Stores staged through LDS for fully coalesced float4 epilogue.
__global__ __launch_bounds__(256, 4)
void graph_embed_kernel(const float4* __restrict__ pos_t,  // (N, B)
                        const float* __restrict__ box,     // (3,)
                        const int*   __restrict__ nbr,     // (N, DEG)
                        float* __restrict__ out)           // y (B,N,8) ++ yv (B,N,8,3)
{
    __shared__ float y_lds[8 * 132];    // [b][i_sub*8 + k], stride 132 (pad)
    __shared__ float yv_lds[8 * 388];   // [b][i_sub*24 + k*3 + c], stride 388 (pad)

    const int tid = threadIdx.x;
    const int t   = blockIdx.x * 256 + tid;   // < 320000 exactly
    const int b   = t & 7;          // lane bits 0-2
    const int jh  = (t >> 3) & 1;   // lane bit 3 (deg half)
    const int i   = t >> 4;         // node, < 20000 exactly
    const int i_sub  = tid >> 4;    // 0..15 within block
    const int i_base = blockIdx.x * 16;

    const float inv2pi = 0.15915494309189535f;
    const float ab0 = box[0] * inv2pi;
    const float ab1 = box[1] * inv2pi;
    const float ab2 = box[2] * inv2pi;
    const float ia0 = 1.0f / ab0;
    const float ia1 = 1.0f / ab1;
    const float ia2 = 1.0f / ab2;

    float h[NB - 1];
#pragma unroll
    for (int k = 0; k < NB - 1; ++k)
        h[k] = __expf(-0.6530612245f * (float)(2 * k + 1));

    const float4 p = pos_t[(size_t)i * BATCH + b];

    float y0[NB], v0[NB], v1[NB], v2[NB];
#pragma unroll
    for (int k = 0; k < NB; ++k) { y0[k] = 0.f; v0[k] = 0.f; v1[k] = 0.f; v2[k] = 0.f; }

    // This thread's 16 neighbors: indices jh*16 .. jh*16+15 (4 int4s, 1 line).
    const int4* __restrict__ row4 = (const int4*)(nbr + (size_t)i * DEG) + jh * 4;
    const int4 rr0 = row4[0], rr1 = row4[1], rr2 = row4[2], rr3 = row4[3];
    const int4 rr[4] = { rr0, rr1, rr2, rr3 };

    // Software pipeline over 4 groups of 4 gathers.
    float4 q0 = pos_t[(size_t)rr[0].x * BATCH + b];
    float4 q1 = pos_t[(size_t)rr[0].y * BATCH + b];
    float4 q2 = pos_t[(size_t)rr[0].z * BATCH + b];
    float4 q3 = pos_t[(size_t)rr[0].w * BATCH + b];

#pragma unroll
    for (int g = 0; g < 4; ++g) {
        float4 n0, n1, n2, n3;
        if (g + 1 < 4) {
            const int4 nx = rr[g + 1];
            n0 = pos_t[(size_t)nx.x * BATCH + b];
            n1 = pos_t[(size_t)nx.y * BATCH + b];
            n2 = pos_t[(size_t)nx.z * BATCH + b];
            n3 = pos_t[(size_t)nx.w * BATCH + b];
        }
        const float4 qs[4] = { q0, q1, q2, q3 };
#pragma unroll
        for (int jj = 0; jj < 4; ++jj) {
            const float4 q = qs[jj];
            const float e0 = ab0 * __sinf((q.x - p.x) * ia0);
            const float e1 = ab1 * __sinf((q.y - p.y) * ia1);
            const float e2 = ab2 * __sinf((q.z - p.z) * ia2);
            const float r  = fmaf(e0, e0, fmaf(e1, e1, e2 * e2));

            const float g2 = EXP2F(r * C2);
            float x = EXP2F(r * r * C1);
#pragma unroll
            for (int k = 0; k < NB; ++k) {
                y0[k] += x;
                v0[k] = fmaf(x, e0, v0[k]);
                v1[k] = fmaf(x, e1, v1[k]);
                v2[k] = fmaf(x, e2, v2[k]);
                if (k < NB - 1) x = x * g2 * h[k];
            }
        }
        q0 = n0; q1 = n1; q2 = n2; q3 = n3;
    }

    // Combine the two deg-halves: partner is lane ^ 8 (same b, same node).
#pragma unroll
    for (int k = 0; k < NB; ++k) {
        y0[k] += __shfl_xor(y0[k], 8);
        v0[k] += __shfl_xor(v0[k], 8);
        v1[k] += __shfl_xor(v1[k], 8);
        v2[k] += __shfl_xor(v2[k], 8);
    }

    // jh==0 lanes hold full sums; stage into LDS.
    if ((tid & 8) == 0) {
        float* yl = y_lds + b * 132 + i_sub * 8;
        float* vl = yv_lds + b * 388 + i_sub * 24;
#pragma unroll
        for (int k = 0; k < NB; ++k) {
            yl[k] = y0[k];
            vl[k * 3 + 0] = v0[k];
            vl[k * 3 + 1] = v1[k];
            vl[k * 3 + 2] = v2[k];
        }
    }
    __syncthreads();

    // Coalesced epilogue. y: 8 b-chunks of 16 nodes * 8 floats = 32 float4 each.
    {
        const int bb  = tid >> 5;        // 0..7
        const int off = tid & 31;        // float4 index within chunk
        *(float4*)(out + (size_t)(bb * NODES + i_base) * NB + off * 4) =
            *(const float4*)(y_lds + bb * 132 + off * 4);
    }
    // yv: 8 b-chunks of 16 nodes * 24 floats = 96 float4 each (768 total).
    float* __restrict__ outv = out + (size_t)BATCH * NODES * NB;
#pragma unroll
    for (int s = 0; s < 3; ++s) {
        const int idx = tid + s * 256;   // < 768
        const int bb  = idx / 96;
        const int rem = idx - bb * 96;
        *(float4*)(outv + (size_t)(bb * NODES + i_base) * (NB * 3) + rem * 4) =
            *(const float4*)(yv_lds + bb * 388 + rem * 4);
    }
}

// Fallback (ws too small): direct-gather version, i-fast mapping.
__global__ __launch_bounds__(256)
void graph_embed_fallback_kernel(const float* __restrict__ pos,
                                 const float* __restrict__ box,
                                 const int*   __restrict__ nbr,
                                 float* __restrict__ out)
{
    const int t = blockIdx.x * blockDim.x + threadIdx.x;
    if (t >= BATCH * NODES) return;
    const int b = t / NODES;
    const int i = t - b * NODES;

    const float inv2pi = 0.15915494309189535f;
    const float ab0 = box[0] * inv2pi, ab1 = box[1] * inv2pi, ab2 = box[2] * inv2pi;
    const float ia0 = 1.0f / ab0, ia1 = 1.0f / ab1, ia2 = 1.0f / ab2;

    float h[NB - 1];
#pragma unroll
    for (int k = 0; k < NB - 1; ++k)
        h[k] = __expf(-0.6530612245f * (float)(2 * k + 1));

    const float* __restrict__ pb = pos + (size_t)b * NODES * 3;
    const float p0 = pb[3 * i + 0], p1 = pb[3 * i + 1], p2 = pb[3 * i + 2];

    float y0[NB], v0[NB], v1[NB], v2[NB];
#pragma unroll
    for (int k = 0; k < NB; ++k) { y0[k] = 0.f; v0[k] = 0.f; v1[k] = 0.f; v2[k] = 0.f; }

    const int* __restrict__ row = nbr + (size_t)i * DEG;
#pragma unroll 4
    for (int j = 0; j < DEG; ++j) {
        const int idx = row[j];
        const float* __restrict__ q = pb + (size_t)idx * 3;
        const float e0 = ab0 * __sinf((q[0] - p0) * ia0);
        const float e1 = ab1 * __sinf((q[1] - p1) * ia1);
        const float e2 = ab2 * __sinf((q[2] - p2) * ia2);
        const float r  = fmaf(e0, e0, fmaf(e1, e1, e2 * e2));
        const float g = EXP2F(r * C2);
        float x = EXP2F(r * r * C1);
#pragma unroll
        for (int k = 0; k < NB; ++k) {
            y0[k] += x;
            v0[k] = fmaf(x, e0, v0[k]);
            v1[k] = fmaf(x, e1, v1[k]);
            v2[k] = fmaf(x, e2, v2[k]);
            if (k < NB - 1) x = x * g * h[k];
        }
    }

    float* __restrict__ yptr = out + (size_t)t * NB;
    *(float4*)(yptr + 0) = make_float4(y0[0], y0[1], y0[2], y0[3]);
    *(float4*)(yptr + 4) = make_float4(y0[4], y0[5], y0[6], y0[7]);
    float* __restrict__ vptr = out + (size_t)BATCH * NODES * NB + (size_t)t * (NB * 3);
    *(float4*)(vptr +  0) = make_float4(v0[0], v1[0], v2[0], v0[1]);
    *(float4*)(vptr +  4) = make_float4(v1[1], v2[1], v0[2], v1[2]);
    *(float4*)(vptr +  8) = make_float4(v2[2], v0[3], v1[3], v2[3]);
    *(float4*)(vptr + 12) = make_float4(v0[4], v1[4], v2[4], v0[5]);
    *(float4*)(vptr + 16) = make_float4(v1[5], v2[5], v0[6], v1[6]);
    *(float4*)(vptr + 20) = make_float4(v2[6], v0[7], v1[7], v2[7]);
}

extern "C" void kernel_launch(void* const* d_in, const int* in_sizes, int n_in,
                              void* d_out, int out_size, void* d_ws, size_t ws_size,
                              hipStream_t stream) {
    const float* pos = (const float*)d_in[0];   // (8, 20000, 3) fp32
    const float* box = (const float*)d_in[1];   // (3,) fp32
    const int*   nbr = (const int*)d_in[2];     // (20000, 32) int32
    float* out = (float*)d_out;

    const int total = BATCH * NODES;
    const size_t packed_bytes = (size_t)total * sizeof(float4);  // 5.12 MB
    if (ws_size >= packed_bytes) {
        float4* pos_t = (float4*)d_ws;
        const int block = 256;
        transpose_pos_kernel<<<(total + block - 1) / block, block, 0, stream>>>(pos, pos_t);
        // 2x deg-split: 320000 threads = 1250 blocks of 256
        graph_embed_kernel<<<(total * 2) / block, block, 0, stream>>>(pos_t, box, nbr, out);
    } else {
        const int block = 256;
        graph_embed_fallback_kernel<<<(total + block - 1) / block, block, 0, stream>>>(pos, box, nbr, out);
    }
}

// Round 5
// 83.187 us; speedup vs baseline: 1.2077x; 1.0090x over previous
//
#include <hip/hip_runtime.h>

static constexpr int BATCH = 8;
static constexpr int NODES = 20000;
static constexpr int DEG   = 32;
static constexpr int NB    = 8;

#if defined(__has_builtin) && __has_builtin(__builtin_amdgcn_exp2f)
#define EXP2F(x) __builtin_amdgcn_exp2f(x)
#else
#define EXP2F(x) exp2f(x)
#endif

typedef float float2v __attribute__((ext_vector_type(2)));

// RBF algebra: sigma = 2.5/8, mu_k = k*2.5/7, D = 0.5*(mu1/sigma)^2 = 0.65306122
//   x_k = x_0 * g^k * e^{-D k^2};  x_0 = exp2(r^2*C1);  g = exp2(r*C2)
// Packed pair ladder: (x_{2p},x_{2p+1}) -> (x_{2p+2},x_{2p+3}) is one packed
// mul by g^2*(e^{-D(8p+4)}, e^{-D(8p+8)}) -> v_pk_fma_f32 throughput.
static constexpr float C1 = -7.3865986f;   // -(0.5/sigma^2)*log2e
static constexpr float C2 = 5.2761417f;    // (mu1/sigma^2)*log2e
static constexpr float H1 = 0.5204500f;    // e^{-D}
static constexpr float S0A = 0.0733695f;   // e^{-4D}
static constexpr float S0B = 0.00538308f;  // e^{-8D}
static constexpr float S1A = 3.94957e-4f;  // e^{-12D}
static constexpr float S1B = 2.89776e-5f;  // e^{-16D}
static constexpr float S2A = 2.12617e-6f;  // e^{-20D}
static constexpr float S2B = 1.55990e-7f;  // e^{-24D}

// pos (B,N,3) -> pos_t (N,B) float4: 8 batch copies of a node = one 128B line.
__global__ __launch_bounds__(256)
void transpose_pos_kernel(const float* __restrict__ pos, float4* __restrict__ pos_t) {
    const int t = blockIdx.x * blockDim.x + threadIdx.x;
    if (t >= BATCH * NODES) return;
    const int b = t / NODES;
    const int i = t - b * NODES;
    pos_t[(size_t)i * BATCH + b] =
        make_float4(pos[3 * t + 0], pos[3 * t + 1], pos[3 * t + 2], 0.0f);
}

// Thread per (node i, batch b, deg-half jh); packed fp32 inner loop.
__global__ __launch_bounds__(256, 4)
void graph_embed_kernel(const float4* __restrict__ pos_t,  // (N, B)
                        const float* __restrict__ box,     // (3,)
                        const int*   __restrict__ nbr,     // (N, DEG)
                        float* __restrict__ out)           // y (B,N,8) ++ yv (B,N,8,3)
{
    __shared__ float y_lds[8 * 132];    // [b][i_sub*8 + k]
    __shared__ float yv_lds[8 * 388];   // [b][i_sub*24 + k*3 + c]

    const int tid = threadIdx.x;
    const int t   = blockIdx.x * 256 + tid;   // < 320000 exactly
    const int b   = t & 7;
    const int jh  = (t >> 3) & 1;
    const int i   = t >> 4;
    const int i_sub  = tid >> 4;
    const int i_base = blockIdx.x * 16;

    const float inv2pi = 0.15915494309189535f;
    const float ab0 = box[0] * inv2pi;
    const float ab1 = box[1] * inv2pi;
    const float ab2 = box[2] * inv2pi;
    const float ia0 = 1.0f / ab0;
    const float ia1 = 1.0f / ab1;
    const float ia2 = 1.0f / ab2;

    const float2v s0 = { S0A, S0B };
    const float2v s1 = { S1A, S1B };
    const float2v s2 = { S2A, S2B };

    const float4 p = pos_t[(size_t)i * BATCH + b];

    float2v yA[4], vA0[4], vA1[4], vA2[4];
#pragma unroll
    for (int pp = 0; pp < 4; ++pp) {
        yA[pp] = (float2v)0.f; vA0[pp] = (float2v)0.f;
        vA1[pp] = (float2v)0.f; vA2[pp] = (float2v)0.f;
    }

    const int4* __restrict__ row4 = (const int4*)(nbr + (size_t)i * DEG) + jh * 4;
    const int4 rr0 = row4[0], rr1 = row4[1], rr2 = row4[2], rr3 = row4[3];
    const int4 rr[4] = { rr0, rr1, rr2, rr3 };

    float4 q0 = pos_t[(size_t)rr[0].x * BATCH + b];
    float4 q1 = pos_t[(size_t)rr[0].y * BATCH + b];
    float4 q2 = pos_t[(size_t)rr[0].z * BATCH + b];
    float4 q3 = pos_t[(size_t)rr[0].w * BATCH + b];

#pragma unroll
    for (int g = 0; g < 4; ++g) {
        float4 n0, n1, n2, n3;
        if (g + 1 < 4) {
            const int4 nx = rr[g + 1];
            n0 = pos_t[(size_t)nx.x * BATCH + b];
            n1 = pos_t[(size_t)nx.y * BATCH + b];
            n2 = pos_t[(size_t)nx.z * BATCH + b];
            n3 = pos_t[(size_t)nx.w * BATCH + b];
        }
        const float4 qs[4] = { q0, q1, q2, q3 };
#pragma unroll
        for (int jj = 0; jj < 4; ++jj) {
            const float4 q = qs[jj];
            const float e0 = ab0 * __sinf((q.x - p.x) * ia0);
            const float e1 = ab1 * __sinf((q.y - p.y) * ia1);
            const float e2 = ab2 * __sinf((q.z - p.z) * ia2);
            const float r  = fmaf(e0, e0, fmaf(e1, e1, e2 * e2));

            const float gg  = EXP2F(r * C2);
            const float gg2 = gg * gg;
            const float x0  = EXP2F(r * r * C1);
            float2v xp = { x0, x0 * gg * H1 };
            const float2v m0 = gg2 * s0;
            const float2v m1 = gg2 * s1;
            const float2v m2 = gg2 * s2;

            yA[0] += xp; vA0[0] += xp * e0; vA1[0] += xp * e1; vA2[0] += xp * e2;
            xp *= m0;
            yA[1] += xp; vA0[1] += xp * e0; vA1[1] += xp * e1; vA2[1] += xp * e2;
            xp *= m1;
            yA[2] += xp; vA0[2] += xp * e0; vA1[2] += xp * e1; vA2[2] += xp * e2;
            xp *= m2;
            yA[3] += xp; vA0[3] += xp * e0; vA1[3] += xp * e1; vA2[3] += xp * e2;
        }
        q0 = n0; q1 = n1; q2 = n2; q3 = n3;
    }

    // Combine the two deg-halves: partner is lane ^ 8.
#pragma unroll
    for (int pp = 0; pp < 4; ++pp) {
        yA[pp].x  += __shfl_xor(yA[pp].x, 8);  yA[pp].y  += __shfl_xor(yA[pp].y, 8);
        vA0[pp].x += __shfl_xor(vA0[pp].x, 8); vA0[pp].y += __shfl_xor(vA0[pp].y, 8);
        vA1[pp].x += __shfl_xor(vA1[pp].x, 8); vA1[pp].y += __shfl_xor(vA1[pp].y, 8);
        vA2[pp].x += __shfl_xor(vA2[pp].x, 8); vA2[pp].y += __shfl_xor(vA2[pp].y, 8);
    }

    if ((tid & 8) == 0) {
        float* yl = y_lds + b * 132 + i_sub * 8;
        float* vl = yv_lds + b * 388 + i_sub * 24;
#pragma unroll
        for (int pp = 0; pp < 4; ++pp) {
            yl[2 * pp]     = yA[pp].x;
            yl[2 * pp + 1] = yA[pp].y;
            vl[6 * pp + 0] = vA0[pp].x;
            vl[6 * pp + 1] = vA1[pp].x;
            vl[6 * pp + 2] = vA2[pp].x;
            vl[6 * pp + 3] = vA0[pp].y;
            vl[6 * pp + 4] = vA1[pp].y;
            vl[6 * pp + 5] = vA2[pp].y;
        }
    }
    __syncthreads();

    // Coalesced epilogue (identical to R4, verified).
    {
        const int bb  = tid >> 5;
        const int off = tid & 31;
        *(float4*)(out + (size_t)(bb * NODES + i_base) * NB + off * 4) =
            *(const float4*)(y_lds + bb * 132 + off * 4);
    }
    float* __restrict__ outv = out + (size_t)BATCH * NODES * NB;
#pragma unroll
    for (int s = 0; s < 3; ++s) {
        const int idx = tid + s * 256;
        const int bb  = idx / 96;
        const int rem = idx - bb * 96;
        *(float4*)(outv + (size_t)(bb * NODES + i_base) * (NB * 3) + rem * 4) =
            *(const float4*)(yv_lds + bb * 388 + rem * 4);
    }
}

// Fallback (ws too small): direct-gather scalar version.
__global__ __launch_bounds__(256)
void graph_embed_fallback_kernel(const float* __restrict__ pos,
                                 const float* __restrict__ box,
                                 const int*   __restrict__ nbr,
                                 float* __restrict__ out)
{
    const int t = blockIdx.x * blockDim.x + threadIdx.x;
    if (t >= BATCH * NODES) return;
    const int b = t / NODES;
    const int i = t - b * NODES;

    const float inv2pi = 0.15915494309189535f;
    const float ab0 = box[0] * inv2pi, ab1 = box[1] * inv2pi, ab2 = box[2] * inv2pi;
    const float ia0 = 1.0f / ab0, ia1 = 1.0f / ab1, ia2 = 1.0f / ab2;

    float h[NB - 1];
#pragma unroll
    for (int k = 0; k < NB - 1; ++k)
        h[k] = __expf(-0.6530612245f * (float)(2 * k + 1));

    const float* __restrict__ pb = pos + (size_t)b * NODES * 3;
    const float p0 = pb[3 * i + 0], p1 = pb[3 * i + 1], p2 = pb[3 * i + 2];

    float y0[NB], v0[NB], v1[NB], v2[NB];
#pragma unroll
    for (int k = 0; k < NB; ++k) { y0[k] = 0.f; v0[k] = 0.f; v1[k] = 0.f; v2[k] = 0.f; }

    const int* __restrict__ row = nbr + (size_t)i * DEG;
#pragma unroll 4
    for (int j = 0; j < DEG; ++j) {
        const int idx = row[j];
        const float* __restrict__ q = pb + (size_t)idx * 3;
        const float e0 = ab0 * __sinf((q[0] - p0) * ia0);
        const float e1 = ab1 * __sinf((q[1] - p1) * ia1);
        const float e2 = ab2 * __sinf((q[2] - p2) * ia2);
        const float r  = fmaf(e0, e0, fmaf(e1, e1, e2 * e2));
        const float g = EXP2F(r * C2);
        float x = EXP2F(r * r * C1);
#pragma unroll
        for (int k = 0; k < NB; ++k) {
            y0[k] += x;
            v0[k] = fmaf(x, e0, v0[k]);
            v1[k] = fmaf(x, e1, v1[k]);
            v2[k] = fmaf(x, e2, v2[k]);
            if (k < NB - 1) x = x * g * h[k];
        }
    }

    float* __restrict__ yptr = out + (size_t)t * NB;
    *(float4*)(yptr + 0) = make_float4(y0[0], y0[1], y0[2], y0[3]);
    *(float4*)(yptr + 4) = make_float4(y0[4], y0[5], y0[6], y0[7]);
    float* __restrict__ vptr = out + (size_t)BATCH * NODES * NB + (size_t)t * (NB * 3);
    *(float4*)(vptr +  0) = make_float4(v0[0], v1[0], v2[0], v0[1]);
    *(float4*)(vptr +  4) = make_float4(v1[1], v2[1], v0[2], v1[2]);
    *(float4*)(vptr +  8) = make_float4(v2[2], v0[3], v1[3], v2[3]);
    *(float4*)(vptr + 12) = make_float4(v0[4], v1[4], v2[4], v0[5]);
    *(float4*)(vptr + 16) = make_float4(v1[5], v2[5], v0[6], v1[6]);
    *(float4*)(vptr + 20) = make_float4(v2[6], v0[7], v1[7], v2[7]);
}

extern "C" void kernel_launch(void* const* d_in, const int* in_sizes, int n_in,
                              void* d_out, int out_size, void* d_ws, size_t ws_size,
                              hipStream_t stream) {
    const float* pos = (const float*)d_in[0];   // (8, 20000, 3) fp32
    const float* box = (const float*)d_in[1];   // (3,) fp32
    const int*   nbr = (const int*)d_in[2];     // (20000, 32) int32
    float* out = (float*)d_out;

    const int total = BATCH * NODES;
    const size_t packed_bytes = (size_t)total * sizeof(float4);  // 5.12 MB
    const int block = 256;
    if (ws_size >= packed_bytes) {
        float4* pos_t = (float4*)d_ws;
        transpose_pos_kernel<<<(total + block - 1) / block, block, 0, stream>>>(pos, pos_t);
        graph_embed_kernel<<<(total * 2) / block, block, 0, stream>>>(pos_t, box, nbr, out);
    } else {
        graph_embed_fallback_kernel<<<(total + block - 1) / block, block, 0, stream>>>(pos, box, nbr, out);
    }
}

// Round 7
// 80.641 us; speedup vs baseline: 1.2458x; 1.0316x over previous
//
#include <hip/hip_runtime.h>

static constexpr int BATCH = 8;
static constexpr int NODES = 20000;
static constexpr int DEG   = 32;
static constexpr int NB    = 8;

#if defined(__has_builtin) && __has_builtin(__builtin_amdgcn_exp2f)
#define EXP2F(x) __builtin_amdgcn_exp2f(x)
#else
#define EXP2F(x) exp2f(x)
#endif

typedef float float2v __attribute__((ext_vector_type(2)));
typedef float float4v __attribute__((ext_vector_type(4)));

// RBF algebra: sigma = 2.5/8, mu_k = k*2.5/7, D = 0.5*(mu1/sigma)^2 = 0.65306122
//   x_k = x_0 * g^k * e^{-D k^2};  x_0 = exp2(r^2*C1);  g = exp2(r*C2)
// Packed pair ladder: (x_{2p},x_{2p+1}) advance by one packed mul with
// g^2*(e^{-D(8p+4)}, e^{-D(8p+8)}).
static constexpr float C1 = -7.3865986f;   // -(0.5/sigma^2)*log2e
static constexpr float C2 = 5.2761417f;    // (mu1/sigma^2)*log2e
static constexpr float H1 = 0.5204500f;    // e^{-D}
static constexpr float S0A = 0.0733695f;   // e^{-4D}
static constexpr float S0B = 0.00538308f;  // e^{-8D}
static constexpr float S1A = 3.94957e-4f;  // e^{-12D}
static constexpr float S1B = 2.89776e-5f;  // e^{-16D}
static constexpr float S2A = 2.12617e-6f;  // e^{-20D}
static constexpr float S2B = 1.55990e-7f;  // e^{-24D}

// pos (B,N,3) -> pos_t (N,B) float4: 8 batch copies of a node = one 128B line.
// Normal (cached) stores on purpose: they seed L2 with the gather working set.
__global__ __launch_bounds__(256)
void transpose_pos_kernel(const float* __restrict__ pos, float4* __restrict__ pos_t) {
    const int t = blockIdx.x * blockDim.x + threadIdx.x;
    if (t >= BATCH * NODES) return;
    const int b = t / NODES;
    const int i = t - b * NODES;
    pos_t[(size_t)i * BATCH + b] =
        make_float4(pos[3 * t + 0], pos[3 * t + 1], pos[3 * t + 2], 0.0f);
}

// Thread per (node i, batch b, deg-half jh); packed fp32 inner loop.
// Output stores are NONTEMPORAL: keeps the 20.5 MB output stream from
// evicting pos_t (5.12 MB) out of the per-XCD 4 MB L2s.
__global__ __launch_bounds__(256, 4)
void graph_embed_kernel(const float4* __restrict__ pos_t,  // (N, B)
                        const float* __restrict__ box,     // (3,)
                        const int*   __restrict__ nbr,     // (N, DEG)
                        float* __restrict__ out)           // y (B,N,8) ++ yv (B,N,8,3)
{
    __shared__ float y_lds[8 * 132];    // [b][i_sub*8 + k]
    __shared__ float yv_lds[8 * 388];   // [b][i_sub*24 + k*3 + c]

    const int tid = threadIdx.x;
    const int t   = blockIdx.x * 256 + tid;   // < 320000 exactly
    const int b   = t & 7;
    const int jh  = (t >> 3) & 1;
    const int i   = t >> 4;
    const int i_sub  = tid >> 4;
    const int i_base = blockIdx.x * 16;

    const float inv2pi = 0.15915494309189535f;
    const float ab0 = box[0] * inv2pi;
    const float ab1 = box[1] * inv2pi;
    const float ab2 = box[2] * inv2pi;
    const float ia0 = 1.0f / ab0;
    const float ia1 = 1.0f / ab1;
    const float ia2 = 1.0f / ab2;

    const float2v s0 = { S0A, S0B };
    const float2v s1 = { S1A, S1B };
    const float2v s2 = { S2A, S2B };

    const float4 p = pos_t[(size_t)i * BATCH + b];

    float2v yA[4], vA0[4], vA1[4], vA2[4];
#pragma unroll
    for (int pp = 0; pp < 4; ++pp) {
        yA[pp] = (float2v)0.f; vA0[pp] = (float2v)0.f;
        vA1[pp] = (float2v)0.f; vA2[pp] = (float2v)0.f;
    }

    const int4* __restrict__ row4 = (const int4*)(nbr + (size_t)i * DEG) + jh * 4;
    const int4 rr0 = row4[0], rr1 = row4[1], rr2 = row4[2], rr3 = row4[3];
    const int4 rr[4] = { rr0, rr1, rr2, rr3 };

    float4 q0 = pos_t[(size_t)rr[0].x * BATCH + b];
    float4 q1 = pos_t[(size_t)rr[0].y * BATCH + b];
    float4 q2 = pos_t[(size_t)rr[0].z * BATCH + b];
    float4 q3 = pos_t[(size_t)rr[0].w * BATCH + b];

#pragma unroll
    for (int g = 0; g < 4; ++g) {
        float4 n0, n1, n2, n3;
        if (g + 1 < 4) {
            const int4 nx = rr[g + 1];
            n0 = pos_t[(size_t)nx.x * BATCH + b];
            n1 = pos_t[(size_t)nx.y * BATCH + b];
            n2 = pos_t[(size_t)nx.z * BATCH + b];
            n3 = pos_t[(size_t)nx.w * BATCH + b];
        }
        const float4 qs[4] = { q0, q1, q2, q3 };
#pragma unroll
        for (int jj = 0; jj < 4; ++jj) {
            const float4 q = qs[jj];
            const float e0 = ab0 * __sinf((q.x - p.x) * ia0);
            const float e1 = ab1 * __sinf((q.y - p.y) * ia1);
            const float e2 = ab2 * __sinf((q.z - p.z) * ia2);
            const float r  = fmaf(e0, e0, fmaf(e1, e1, e2 * e2));

            const float gg  = EXP2F(r * C2);
            const float gg2 = gg * gg;
            const float x0  = EXP2F(r * r * C1);
            float2v xp = { x0, x0 * gg * H1 };
            const float2v m0 = gg2 * s0;
            const float2v m1 = gg2 * s1;
            const float2v m2 = gg2 * s2;

            yA[0] += xp; vA0[0] += xp * e0; vA1[0] += xp * e1; vA2[0] += xp * e2;
            xp *= m0;
            yA[1] += xp; vA0[1] += xp * e0; vA1[1] += xp * e1; vA2[1] += xp * e2;
            xp *= m1;
            yA[2] += xp; vA0[2] += xp * e0; vA1[2] += xp * e1; vA2[2] += xp * e2;
            xp *= m2;
            yA[3] += xp; vA0[3] += xp * e0; vA1[3] += xp * e1; vA2[3] += xp * e2;
        }
        q0 = n0; q1 = n1; q2 = n2; q3 = n3;
    }

    // Combine the two deg-halves: partner is lane ^ 8.
#pragma unroll
    for (int pp = 0; pp < 4; ++pp) {
        yA[pp].x  += __shfl_xor(yA[pp].x, 8);  yA[pp].y  += __shfl_xor(yA[pp].y, 8);
        vA0[pp].x += __shfl_xor(vA0[pp].x, 8); vA0[pp].y += __shfl_xor(vA0[pp].y, 8);
        vA1[pp].x += __shfl_xor(vA1[pp].x, 8); vA1[pp].y += __shfl_xor(vA1[pp].y, 8);
        vA2[pp].x += __shfl_xor(vA2[pp].x, 8); vA2[pp].y += __shfl_xor(vA2[pp].y, 8);
    }

    if ((tid & 8) == 0) {
        float* yl = y_lds + b * 132 + i_sub * 8;
        float* vl = yv_lds + b * 388 + i_sub * 24;
#pragma unroll
        for (int pp = 0; pp < 4; ++pp) {
            yl[2 * pp]     = yA[pp].x;
            yl[2 * pp + 1] = yA[pp].y;
            vl[6 * pp + 0] = vA0[pp].x;
            vl[6 * pp + 1] = vA1[pp].x;
            vl[6 * pp + 2] = vA2[pp].x;
            vl[6 * pp + 3] = vA0[pp].y;
            vl[6 * pp + 4] = vA1[pp].y;
            vl[6 * pp + 5] = vA2[pp].y;
        }
    }
    __syncthreads();

    // Coalesced epilogue, nontemporal stores (keep pos_t resident in L2).
    {
        const int bb  = tid >> 5;
        const int off = tid & 31;
        float4v* dst = (float4v*)(out + (size_t)(bb * NODES + i_base) * NB + off * 4);
        const float4v val = *(const float4v*)(y_lds + bb * 132 + off * 4);
        __builtin_nontemporal_store(val, dst);
    }
    float* __restrict__ outv = out + (size_t)BATCH * NODES * NB;
#pragma unroll
    for (int s = 0; s < 3; ++s) {
        const int idx = tid + s * 256;
        const int bb  = idx / 96;
        const int rem = idx - bb * 96;
        float4v* dst = (float4v*)(outv + (size_t)(bb * NODES + i_base) * (NB * 3) + rem * 4);
        const float4v val = *(const float4v*)(yv_lds + bb * 388 + rem * 4);
        __builtin_nontemporal_store(val, dst);
    }
}

// Fallback (ws too small): direct-gather scalar version.
__global__ __launch_bounds__(256)
void graph_embed_fallback_kernel(const float* __restrict__ pos,
                                 const float* __restrict__ box,
                                 const int*   __restrict__ nbr,
                                 float* __restrict__ out)
{
    const int t = blockIdx.x * blockDim.x + threadIdx.x;
    if (t >= BATCH * NODES) return;
    const int b = t / NODES;
    const int i = t - b * NODES;

    const float inv2pi = 0.15915494309189535f;
    const float ab0 = box[0] * inv2pi, ab1 = box[1] * inv2pi, ab2 = box[2] * inv2pi;
    const float ia0 = 1.0f / ab0, ia1 = 1.0f / ab1, ia2 = 1.0f / ab2;

    float h[NB - 1];
#pragma unroll
    for (int k = 0; k < NB - 1; ++k)
        h[k] = __expf(-0.6530612245f * (float)(2 * k + 1));

    const float* __restrict__ pb = pos + (size_t)b * NODES * 3;
    const float p0 = pb[3 * i + 0], p1 = pb[3 * i + 1], p2 = pb[3 * i + 2];

    float y0[NB], v0[NB], v1[NB], v2[NB];
#pragma unroll
    for (int k = 0; k < NB; ++k) { y0[k] = 0.f; v0[k] = 0.f; v1[k] = 0.f; v2[k] = 0.f; }

    const int* __restrict__ row = nbr + (size_t)i * DEG;
#pragma unroll 4
    for (int j = 0; j < DEG; ++j) {
        const int idx = row[j];
        const float* __restrict__ q = pb + (size_t)idx * 3;
        const float e0 = ab0 * __sinf((q[0] - p0) * ia0);
        const float e1 = ab1 * __sinf((q[1] - p1) * ia1);
        const float e2 = ab2 * __sinf((q[2] - p2) * ia2);
        const float r  = fmaf(e0, e0, fmaf(e1, e1, e2 * e2));
        const float g = EXP2F(r * C2);
        float x = EXP2F(r * r * C1);
#pragma unroll
        for (int k = 0; k < NB; ++k) {
            y0[k] += x;
            v0[k] = fmaf(x, e0, v0[k]);
            v1[k] = fmaf(x, e1, v1[k]);
            v2[k] = fmaf(x, e2, v2[k]);
            if (k < NB - 1) x = x * g * h[k];
        }
    }

    float* __restrict__ yptr = out + (size_t)t * NB;
    *(float4*)(yptr + 0) = make_float4(y0[0], y0[1], y0[2], y0[3]);
    *(float4*)(yptr + 4) = make_float4(y0[4], y0[5], y0[6], y0[7]);
    float* __restrict__ vptr = out + (size_t)BATCH * NODES * NB + (size_t)t * (NB * 3);
    *(float4*)(vptr +  0) = make_float4(v0[0], v1[0], v2[0], v0[1]);
    *(float4*)(vptr +  4) = make_float4(v1[1], v2[1], v0[2], v1[2]);
    *(float4*)(vptr +  8) = make_float4(v2[2], v0[3], v1[3], v2[3]);
    *(float4*)(vptr + 12) = make_float4(v0[4], v1[4], v2[4], v0[5]);
    *(float4*)(vptr + 16) = make_float4(v1[5], v2[5], v0[6], v1[6]);
    *(float4*)(vptr + 20) = make_float4(v2[6], v0[7], v1[7], v2[7]);
}

extern "C" void kernel_launch(void* const* d_in, const int* in_sizes, int n_in,
                              void* d_out, int out_size, void* d_ws, size_t ws_size,
                              hipStream_t stream) {
    const float* pos = (const float*)d_in[0];   // (8, 20000, 3) fp32
    const float* box = (const float*)d_in[1];   // (3,) fp32
    const int*   nbr = (const int*)d_in[2];     // (20000, 32) int32
    float* out = (float*)d_out;

    const int total = BATCH * NODES;
    const size_t packed_bytes = (size_t)total * sizeof(float4);  // 5.12 MB
    const int block = 256;
    if (ws_size >= packed_bytes) {
        float4* pos_t = (float4*)d_ws;
        transpose_pos_kernel<<<(total + block - 1) / block, block, 0, stream>>>(pos, pos_t);
        graph_embed_kernel<<<(total * 2) / block, block, 0, stream>>>(pos_t, box, nbr, out);
    } else {
        graph_embed_fallback_kernel<<<(total + block - 1) / block, block, 0, stream>>>(pos, box, nbr, out);
    }
}